// Round 1
// baseline (67.984 us; speedup 1.0000x reference)
//
#include <hip/hip_runtime.h>

#define NPTS 4096
#define BATCH 8
#define YC 512          // Y-chunk size (points staged in LDS per block)
#define QPB 1024        // queries per block
#define QPT 4           // queries per thread (QPB / 256)
#define YCH (NPTS/YC)   // 8 Y-chunks
#define QCH (NPTS/QPB)  // 4 query-chunks
#define BIGF 1e10f

// monotone float -> uint key (handles negatives), so unsigned atomicMin == float min
__device__ __forceinline__ unsigned f2key(float f) {
    unsigned u = __float_as_uint(f);
    return u ^ ((u & 0x80000000u) ? 0xFFFFFFFFu : 0x80000000u);
}
__device__ __forceinline__ float key2f(unsigned k) {
    unsigned u = (k & 0x80000000u) ? (k ^ 0x80000000u) : ~k;
    return __uint_as_float(u);
}

__global__ __launch_bounds__(256) void init_ws_kernel(unsigned* __restrict__ wmin) {
    int i = blockIdx.x * 256 + threadIdx.x;
    if (i < 2 * BATCH * NPTS) wmin[i] = 0xFFFFFFFFu;
}

// For each (dir, b): queries X, reference set Y with mask on Y side.
// dir 0: X = clean = points+target, Y = predp = points+pred   (-> min_x)
// dir 1: X = predp = points+pred,  Y = clean = points+target  (-> min_y)
// We min over e = y2 + w - 2*dot(x,y); final min dist = x2 + min_e (clamped >= 0 later).
__global__ __launch_bounds__(256) void chamfer_min_kernel(
    const float* __restrict__ pred, const float* __restrict__ target,
    const int* __restrict__ mask, const float* __restrict__ points,
    unsigned* __restrict__ wmin)
{
    __shared__ float4 ytile[YC];

    int bid = blockIdx.x;
    int yc  = bid & (YCH - 1);   bid >>= 3;  // 8 y-chunks
    int qc  = bid & (QCH - 1);   bid >>= 2;  // 4 q-chunks
    int b   = bid & (BATCH - 1); bid >>= 3;  // 8 batches
    int dir = bid;                            // 2 directions

    const float* __restrict__ yres = dir ? target : pred;
    const float* __restrict__ xres = dir ? pred : target;

    int t = threadIdx.x;

    // stage Y chunk into LDS: (x, y, z, y2 + mask_penalty)
    for (int i = t; i < YC; i += 256) {
        int g = b * NPTS + yc * YC + i;
        float yx = points[g * 3 + 0] + yres[g * 3 + 0];
        float yy = points[g * 3 + 1] + yres[g * 3 + 1];
        float yz = points[g * 3 + 2] + yres[g * 3 + 2];
        float y2 = yx * yx + yy * yy + yz * yz;
        float w  = mask[g] ? y2 : (y2 + BIGF);
        ytile[i] = make_float4(yx, yy, yz, w);
    }
    __syncthreads();

    float qx[QPT], qy[QPT], qz[QPT], mn[QPT];
#pragma unroll
    for (int k = 0; k < QPT; k++) {
        int g = b * NPTS + qc * QPB + k * 256 + t;
        qx[k] = points[g * 3 + 0] + xres[g * 3 + 0];
        qy[k] = points[g * 3 + 1] + xres[g * 3 + 1];
        qz[k] = points[g * 3 + 2] + xres[g * 3 + 2];
        mn[k] = 3.0e38f;
    }

#pragma unroll 2
    for (int j = 0; j < YC; j++) {
        float4 y = ytile[j];  // uniform address -> LDS broadcast, no bank conflict
#pragma unroll
        for (int k = 0; k < QPT; k++) {
            float dot = fmaf(qz[k], y.z, fmaf(qy[k], y.y, qx[k] * y.x));
            float e   = fmaf(-2.0f, dot, y.w);
            mn[k] = fminf(mn[k], e);
        }
    }

    unsigned* base = wmin + (dir * BATCH + b) * NPTS + qc * QPB;
#pragma unroll
    for (int k = 0; k < QPT; k++) {
        atomicMin(base + k * 256 + t, f2key(mn[k]));
    }
}

__global__ __launch_bounds__(1024) void reduce_kernel(
    const float* __restrict__ pred, const float* __restrict__ target,
    const int* __restrict__ mask, const float* __restrict__ points,
    const unsigned* __restrict__ wmin, float* __restrict__ out)
{
    __shared__ float s_sum[16], s_cnt[16];
    __shared__ float s_total;
    int t = threadIdx.x;
    if (t == 0) s_total = 0.0f;

    for (int b = 0; b < BATCH; b++) {
        float sum = 0.0f, cnt = 0.0f;
        for (int n = t; n < NPTS; n += 1024) {
            int g = b * NPTS + n;
            if (mask[g]) {
                float px = points[g * 3], py = points[g * 3 + 1], pz = points[g * 3 + 2];
                float cx = px + target[g * 3], cy = py + target[g * 3 + 1], cz = pz + target[g * 3 + 2];
                float ex = px + pred[g * 3],   ey = py + pred[g * 3 + 1],   ez = pz + pred[g * 3 + 2];
                float x2c = cx * cx + cy * cy + cz * cz;
                float x2p = ex * ex + ey * ey + ez * ez;
                float e0 = key2f(wmin[(0 * BATCH + b) * NPTS + n]);
                float e1 = key2f(wmin[(1 * BATCH + b) * NPTS + n]);
                sum += fmaxf(x2c + e0, 0.0f) + fmaxf(x2p + e1, 0.0f);
                cnt += 1.0f;
            }
        }
        // wave64 reduction
        for (int off = 32; off; off >>= 1) {
            sum += __shfl_down(sum, off, 64);
            cnt += __shfl_down(cnt, off, 64);
        }
        if ((t & 63) == 0) { s_sum[t >> 6] = sum; s_cnt[t >> 6] = cnt; }
        __syncthreads();
        if (t == 0) {
            float S = 0.0f, C = 0.0f;
            for (int w = 0; w < 16; w++) { S += s_sum[w]; C += s_cnt[w]; }
            s_total += S / C;
        }
        __syncthreads();
    }
    if (t == 0) out[0] = s_total / (float)BATCH;
}

extern "C" void kernel_launch(void* const* d_in, const int* in_sizes, int n_in,
                              void* d_out, int out_size, void* d_ws, size_t ws_size,
                              hipStream_t stream) {
    const float* pred   = (const float*)d_in[0];
    const float* target = (const float*)d_in[1];
    const int*   mask   = (const int*)d_in[2];
    const float* points = (const float*)d_in[3];
    float* out = (float*)d_out;
    unsigned* wmin = (unsigned*)d_ws;  // 2 * BATCH * NPTS uints = 256 KB

    init_ws_kernel<<<(2 * BATCH * NPTS + 255) / 256, 256, 0, stream>>>(wmin);
    chamfer_min_kernel<<<2 * BATCH * QCH * YCH, 256, 0, stream>>>(pred, target, mask, points, wmin);
    reduce_kernel<<<1, 1024, 0, stream>>>(pred, target, mask, points, wmin, out);
}

// Round 2
// 33.671 us; speedup vs baseline: 2.0191x; 2.0191x over previous
//
#include <hip/hip_runtime.h>

#define NPTS 4096
#define BATCH 8
#define YC 512          // Y points staged in LDS per block
#define QPB 1024        // queries per block
#define QPT 4           // queries per thread
#define YCH 8           // NPTS / YC
#define QCH 4           // NPTS / QPB
#define BIGF 1e10f

// Kernel A: for each (dir, b, qc, yc) block, partial min over its Y-chunk of
//   d = x2 + y2 + penalty - 2 x.y, written (no atomics) to pmin[(dir*8+b)*8+yc][n].
// dir 0: X = clean = points+target, Y = predp = points+pred   (-> min_x)
// dir 1: X = predp = points+pred,  Y = clean = points+target  (-> min_y)
__global__ __launch_bounds__(256) void chamfer_partial_kernel(
    const float* __restrict__ pred, const float* __restrict__ target,
    const int* __restrict__ mask, const float* __restrict__ points,
    float* __restrict__ pmin)
{
    __shared__ float4 ytile[YC];

    int bid = blockIdx.x;
    int yc  = bid & 7; bid >>= 3;
    int qc  = bid & 3; bid >>= 2;
    int b   = bid & 7; bid >>= 3;
    int dir = bid;

    const float* __restrict__ yres = dir ? target : pred;
    const float* __restrict__ xres = dir ? pred : target;

    int t = threadIdx.x;

    // stage Y chunk: (x, y, z, y2 + mask_penalty)
    for (int i = t; i < YC; i += 256) {
        int g = b * NPTS + yc * YC + i;
        float yx = points[g * 3 + 0] + yres[g * 3 + 0];
        float yy = points[g * 3 + 1] + yres[g * 3 + 1];
        float yz = points[g * 3 + 2] + yres[g * 3 + 2];
        float y2 = yx * yx + yy * yy + yz * yz;
        float w  = mask[g] ? y2 : (y2 + BIGF);
        ytile[i] = make_float4(yx, yy, yz, w);
    }
    __syncthreads();

    // queries: hold -2*x components and x2 in registers
    float q2x[QPT], q2y[QPT], q2z[QPT], x2[QPT], mn[QPT];
#pragma unroll
    for (int k = 0; k < QPT; k++) {
        int g = b * NPTS + qc * QPB + k * 256 + t;
        float qx = points[g * 3 + 0] + xres[g * 3 + 0];
        float qy = points[g * 3 + 1] + xres[g * 3 + 1];
        float qz = points[g * 3 + 2] + xres[g * 3 + 2];
        x2[k]  = qx * qx + qy * qy + qz * qz;
        q2x[k] = -2.0f * qx;
        q2y[k] = -2.0f * qy;
        q2z[k] = -2.0f * qz;
        mn[k]  = 3.0e38f;
    }

#pragma unroll 4
    for (int j = 0; j < YC; j++) {
        float4 y = ytile[j];  // uniform address -> LDS broadcast
#pragma unroll
        for (int k = 0; k < QPT; k++) {
            float e = fmaf(q2z[k], y.z, fmaf(q2y[k], y.y, fmaf(q2x[k], y.x, y.w)));
            mn[k] = fminf(mn[k], e);
        }
    }

    float* base = pmin + ((dir * 8 + b) * 8 + yc) * NPTS + qc * QPB;
#pragma unroll
    for (int k = 0; k < QPT; k++) {
        base[k * 256 + t] = x2[k] + mn[k];  // clamped >= 0 later
    }
}

// Kernel B: per (batch, 512-point segment) block: min the 8 yc-partials per dir,
// clamp, row-mask, accumulate sum & count; write block partials to `part`.
__global__ __launch_bounds__(256) void reduce1_kernel(
    const int* __restrict__ mask, const float* __restrict__ pmin,
    float* __restrict__ part)
{
    __shared__ float s_sum[4], s_cnt[4];
    int blk = blockIdx.x;           // 64 = 8 batches * 8 segments
    int b = blk >> 3, seg = blk & 7;
    int t = threadIdx.x;

    float sum = 0.0f, cnt = 0.0f;
#pragma unroll
    for (int s = 0; s < 2; s++) {
        int n = seg * 512 + s * 256 + t;
        if (mask[b * NPTS + n]) {
            const float* p0 = pmin + ((0 * 8 + b) * 8) * NPTS + n;
            const float* p1 = pmin + ((1 * 8 + b) * 8) * NPTS + n;
            float m0 = p0[0], m1 = p1[0];
#pragma unroll
            for (int yc = 1; yc < 8; yc++) {
                m0 = fminf(m0, p0[yc * NPTS]);
                m1 = fminf(m1, p1[yc * NPTS]);
            }
            sum += fmaxf(m0, 0.0f) + fmaxf(m1, 0.0f);
            cnt += 1.0f;
        }
    }
    // wave64 + block reduction
    for (int off = 32; off; off >>= 1) {
        sum += __shfl_down(sum, off, 64);
        cnt += __shfl_down(cnt, off, 64);
    }
    if ((t & 63) == 0) { s_sum[t >> 6] = sum; s_cnt[t >> 6] = cnt; }
    __syncthreads();
    if (t == 0) {
        float S = 0.0f, C = 0.0f;
#pragma unroll
        for (int w = 0; w < 4; w++) { S += s_sum[w]; C += s_cnt[w]; }
        part[blk * 2 + 0] = S;
        part[blk * 2 + 1] = C;
    }
}

// Kernel C: combine 64 block partials -> scalar loss.
__global__ __launch_bounds__(64) void final_kernel(
    const float* __restrict__ part, float* __restrict__ out)
{
    int t = threadIdx.x;
    float v = 0.0f;
    if (t < BATCH) {
        float S = 0.0f, C = 0.0f;
#pragma unroll
        for (int seg = 0; seg < 8; seg++) {
            S += part[(t * 8 + seg) * 2 + 0];
            C += part[(t * 8 + seg) * 2 + 1];
        }
        v = S / C;
    }
    for (int off = 4; off; off >>= 1) v += __shfl_down(v, off, 64);
    if (t == 0) out[0] = v / (float)BATCH;
}

extern "C" void kernel_launch(void* const* d_in, const int* in_sizes, int n_in,
                              void* d_out, int out_size, void* d_ws, size_t ws_size,
                              hipStream_t stream) {
    const float* pred   = (const float*)d_in[0];
    const float* target = (const float*)d_in[1];
    const int*   mask   = (const int*)d_in[2];
    const float* points = (const float*)d_in[3];
    float* out = (float*)d_out;

    float* pmin = (float*)d_ws;                      // 2*8*8*4096 floats = 2 MB
    float* part = pmin + 2 * 8 * 8 * NPTS;           // 128 floats

    chamfer_partial_kernel<<<2 * BATCH * QCH * YCH, 256, 0, stream>>>(pred, target, mask, points, pmin);
    reduce1_kernel<<<BATCH * 8, 256, 0, stream>>>(mask, pmin, part);
    final_kernel<<<1, 64, 0, stream>>>(part, out);
}

// Round 3
// 32.518 us; speedup vs baseline: 2.0906x; 1.0354x over previous
//
#include <hip/hip_runtime.h>

#define NPTS 4096
#define BATCH 8
#define YC 512          // Y points staged in LDS per block
#define YP (YC/2)       // Y pairs
#define QPB 1024        // queries per block
#define QPT 4           // queries per thread
#define YCH 8           // NPTS / YC
#define QCH 4           // NPTS / QPB
#define BIGF 1e10f

typedef float f2 __attribute__((ext_vector_type(2)));

// Kernel A: for each (dir, b, qc, yc) block, partial min over its Y-chunk of
//   d = x2 + y2 + penalty - 2 x.y, written to pmin[(dir*8+b)*8+yc][n].
// dir 0: X = clean = points+target, Y = predp = points+pred   (-> min_x)
// dir 1: X = predp = points+pred,  Y = clean = points+target  (-> min_y)
// Inner loop is vectorized over PAIRS of Y points: f2 lanes = (y_{2j}, y_{2j+1});
// query coefficients are splat once outside the loop -> v_pk_fma_f32 chains +
// v_min3_f32, no in-loop splats.
__global__ __launch_bounds__(256) void chamfer_partial_kernel(
    const float* __restrict__ pred, const float* __restrict__ target,
    const int* __restrict__ mask, const float* __restrict__ points,
    float* __restrict__ pmin, float* __restrict__ out)
{
    __shared__ float4 tA[YP];   // (x0, x1, yy0, yy1)
    __shared__ float4 tB[YP];   // (z0, z1, w0,  w1)

    if (blockIdx.x == 0 && threadIdx.x == 0) out[0] = 0.0f;  // re-zeroed every replay

    int bid = blockIdx.x;
    int yc  = bid & 7; bid >>= 3;
    int qc  = bid & 3; bid >>= 2;
    int b   = bid & 7; bid >>= 3;
    int dir = bid;

    const float* __restrict__ yres = dir ? target : pred;
    const float* __restrict__ xres = dir ? pred : target;

    int t = threadIdx.x;

    // stage one Y pair per thread: 256 threads == 256 pairs == 512 points
    {
        int g0 = b * NPTS + yc * YC + 2 * t;
        float x0 = points[g0 * 3 + 0] + yres[g0 * 3 + 0];
        float y0 = points[g0 * 3 + 1] + yres[g0 * 3 + 1];
        float z0 = points[g0 * 3 + 2] + yres[g0 * 3 + 2];
        float x1 = points[g0 * 3 + 3] + yres[g0 * 3 + 3];
        float y1 = points[g0 * 3 + 4] + yres[g0 * 3 + 4];
        float z1 = points[g0 * 3 + 5] + yres[g0 * 3 + 5];
        float w0 = x0 * x0 + y0 * y0 + z0 * z0;
        float w1 = x1 * x1 + y1 * y1 + z1 * z1;
        if (!mask[g0])     w0 += BIGF;
        if (!mask[g0 + 1]) w1 += BIGF;
        tA[t] = make_float4(x0, x1, y0, y1);
        tB[t] = make_float4(z0, z1, w0, w1);
    }
    __syncthreads();

    // queries: hold -2*x components (splat to both f2 lanes) and x2 in registers
    f2 q2x[QPT], q2y[QPT], q2z[QPT];
    float x2[QPT], mn[QPT];
#pragma unroll
    for (int k = 0; k < QPT; k++) {
        int g = b * NPTS + qc * QPB + k * 256 + t;
        float qx = points[g * 3 + 0] + xres[g * 3 + 0];
        float qy = points[g * 3 + 1] + xres[g * 3 + 1];
        float qz = points[g * 3 + 2] + xres[g * 3 + 2];
        x2[k] = qx * qx + qy * qy + qz * qz;
        float ax = -2.0f * qx, ay = -2.0f * qy, az = -2.0f * qz;
        q2x[k] = (f2){ax, ax};
        q2y[k] = (f2){ay, ay};
        q2z[k] = (f2){az, az};
        mn[k]  = 3.0e38f;
    }

#pragma unroll 4
    for (int j = 0; j < YP; j++) {
        float4 A = tA[j];   // uniform address -> LDS broadcast
        float4 B = tB[j];
        f2 yx = (f2){A.x, A.y};
        f2 yy = (f2){A.z, A.w};
        f2 yz = (f2){B.x, B.y};
        f2 yw = (f2){B.z, B.w};
#pragma unroll
        for (int k = 0; k < QPT; k++) {
            f2 e = __builtin_elementwise_fma(q2z[k], yz,
                   __builtin_elementwise_fma(q2y[k], yy,
                   __builtin_elementwise_fma(q2x[k], yx, yw)));
            mn[k] = fminf(fminf(mn[k], e.x), e.y);   // -> v_min3_f32
        }
    }

    float* base = pmin + ((dir * 8 + b) * 8 + yc) * NPTS + qc * QPB;
#pragma unroll
    for (int k = 0; k < QPT; k++) {
        base[k * 256 + t] = x2[k] + mn[k];  // clamped >= 0 later
    }
}

// Kernel B: one block per batch. Min the 8 yc-partials per dir, clamp, row-mask,
// sum & count, then one atomicAdd of (S/C)/BATCH into out (zeroed by kernel A).
__global__ __launch_bounds__(1024) void reduce_kernel(
    const int* __restrict__ mask, const float* __restrict__ pmin,
    float* __restrict__ out)
{
    __shared__ float s_sum[16], s_cnt[16];
    int b = blockIdx.x;
    int t = threadIdx.x;

    float sum = 0.0f, cnt = 0.0f;
#pragma unroll
    for (int s = 0; s < 4; s++) {
        int n = s * 1024 + t;
        if (mask[b * NPTS + n]) {
            const float* p0 = pmin + ((0 * 8 + b) * 8) * NPTS + n;
            const float* p1 = pmin + ((1 * 8 + b) * 8) * NPTS + n;
            float m0 = p0[0], m1 = p1[0];
#pragma unroll
            for (int yc = 1; yc < 8; yc++) {
                m0 = fminf(m0, p0[yc * NPTS]);
                m1 = fminf(m1, p1[yc * NPTS]);
            }
            sum += fmaxf(m0, 0.0f) + fmaxf(m1, 0.0f);
            cnt += 1.0f;
        }
    }
    for (int off = 32; off; off >>= 1) {
        sum += __shfl_down(sum, off, 64);
        cnt += __shfl_down(cnt, off, 64);
    }
    if ((t & 63) == 0) { s_sum[t >> 6] = sum; s_cnt[t >> 6] = cnt; }
    __syncthreads();
    if (t == 0) {
        float S = 0.0f, C = 0.0f;
#pragma unroll
        for (int w = 0; w < 16; w++) { S += s_sum[w]; C += s_cnt[w]; }
        atomicAdd(out, (S / C) * (1.0f / (float)BATCH));
    }
}

extern "C" void kernel_launch(void* const* d_in, const int* in_sizes, int n_in,
                              void* d_out, int out_size, void* d_ws, size_t ws_size,
                              hipStream_t stream) {
    const float* pred   = (const float*)d_in[0];
    const float* target = (const float*)d_in[1];
    const int*   mask   = (const int*)d_in[2];
    const float* points = (const float*)d_in[3];
    float* out = (float*)d_out;

    float* pmin = (float*)d_ws;   // 2*8*8*4096 floats = 2 MB

    chamfer_partial_kernel<<<2 * BATCH * QCH * YCH, 256, 0, stream>>>(pred, target, mask, points, pmin, out);
    reduce_kernel<<<BATCH, 1024, 0, stream>>>(mask, pmin, out);
}